// Round 13
// baseline (112.390 us; speedup 1.0000x reference)
//
#include <hip/hip_runtime.h>
#include <math.h>

#define HD 256
#define SEQ 4096
#define NR 16384
#define NHEADS 4
#define EPSV 1e-5f
#define LDP 72    // padded LDS row stride for GEMM K-tiles
#define ZLDP 264  // padded LDS row stride for 256-wide row tiles
#define SROWS 64  // rows per block
#define SHALO 15  // 7 below + 8 above
#define SLDP 264  // halo-tile LDS row stride

typedef __attribute__((ext_vector_type(8))) short bf16x8;
typedef __attribute__((ext_vector_type(4))) float f32x4;

__device__ inline short f2bf(float f) {
    unsigned u = __float_as_uint(f);
    u += 0x7FFF + ((u >> 16) & 1);     // round-to-nearest-even
    return (short)(u >> 16);
}
__device__ inline float bf2f(short s) {
    return __uint_as_float(((unsigned)(unsigned short)s) << 16);
}

// Stage a [256 x 64] bf16 weight tile into padded LDS. Coalesced 16B chunks.
__device__ inline void stage_w(const short* __restrict__ src, int src_stride,
                               int k0, short* lds)
{
    int t = threadIdx.x;
#pragma unroll
    for (int c = 0; c < 8; ++c) {
        int idx = c * 256 + t;
        int r = idx >> 3, kg = idx & 7;
        bf16x8 v = *(const bf16x8*)(src + (size_t)r * src_stride + k0 + kg * 8);
        *(bf16x8*)(lds + r * LDP + kg * 8) = v;
    }
}

// ---------------------------------------------------------------------------
// Weight prep: transpose+cast Wc/Wa/Wg/Wp to bf16 B^T. grid (32,4).
// ---------------------------------------------------------------------------
__global__ __launch_bounds__(256) void prep_w(
    const float* __restrict__ Wc, const float* __restrict__ Wa,
    const float* __restrict__ Wg, const float* __restrict__ Wp,
    short* __restrict__ WcT, short* __restrict__ WaT,
    short* __restrict__ WgT, short* __restrict__ WpT)
{
    __shared__ float lds[64][65];
    int task = blockIdx.y;
    int bx = blockIdx.x;
    int t = threadIdx.x;
    const float* W; short* Wt; int K;
    if (task == 0)      { W = Wc; Wt = WcT; K = 256; }
    else if (task == 1) { W = Wa; Wt = WaT; K = 256; }
    else if (task == 2) { W = Wg; Wt = WgT; K = 512; }
    else                { W = Wp; Wt = WpT; K = 256; }
    int ntiles = (K >> 6) * 4;
    if (bx >= ntiles) return;
    int k0 = (bx >> 2) * 64, n0 = (bx & 3) * 64;
    int ty = t >> 6, tx = t & 63;
#pragma unroll
    for (int s = 0; s < 16; ++s) {
        int r = s * 4 + ty;
        lds[r][tx] = W[(size_t)(k0 + r) * 256 + n0 + tx];
    }
    __syncthreads();
#pragma unroll
    for (int s = 0; s < 16; ++s) {
        int rn = s * 4 + ty;
        Wt[(size_t)(n0 + rn) * K + k0 + tx] = f2bf(lds[tx][rn]);
    }
}

// ---------------------------------------------------------------------------
// Fused head+middle: block owns 64 rows (XCD-swizzled, grid 256).
//  stencil: 79-row fp32 x halo -> bf16 lH; xb -> global
//  pass G1: G1 = xb@Wg_top   (A=lH, lB in region2 before y exists)
//  y -> lYZ (region2); pass Wc: z = y@Wc + bc + xb -> LN stats -> LN(z) -> lYZ
//  pass Wa: h = LN(z)@Wa -> global; es/et (wave-local)
// LDS: region1 41.7K (lH / lB) | region2 36.9K (lB-G1 / lYZ) | red 1K = 79.6K
// ---------------------------------------------------------------------------
__global__ __launch_bounds__(256) void stencil_gemm(
    const float* __restrict__ x, const short* __restrict__ WcT,
    const float* __restrict__ bc, const short* __restrict__ WaT,
    const short* __restrict__ WgT,
    const float* __restrict__ lng, const float* __restrict__ lnb,
    const float* __restrict__ a_src, const float* __restrict__ a_tgt,
    short* __restrict__ xb, short* __restrict__ hb, short* __restrict__ G1,
    float* __restrict__ es, float* __restrict__ et)
{
    __shared__ __align__(16) char smem[79616];
    short* lH  = (short*)smem;               // 79 x SLDP (stencil, A for G1 pass)
    short* lB1 = (short*)smem;               // 256 x LDP (Wc/Wa passes; lH dead)
    short* lB2 = (short*)(smem + 41728);     // 256 x LDP (G1 pass only)
    short* lYZ = (short*)(smem + 41728);     // 64 x ZLDP (y, then LN(z))
    float* red_s = (float*)(smem + 78592);   // [2][64]
    float* red_q = red_s + 128;

    int t = threadIdx.x;
    int bid = blockIdx.x;
    int swz = (bid & 7) * 32 + (bid >> 3);   // 256 blocks, 8 XCDs, chunk 32
    int m0 = swz * SROWS;
    int batch_base = m0 & ~(SEQ - 1);

    // ---- stencil stage: 79 rows fp32 -> bf16 lH ----
    for (int i = t; i < (SROWS + SHALO) * 64; i += 256) {
        int r = i >> 6, c4 = (i & 63) * 4;
        int grow = m0 - 7 + r;
        short4 o4 = {0, 0, 0, 0};
        if (grow >= batch_base && grow < batch_base + SEQ) {
            float4 v = *(const float4*)(x + (size_t)grow * HD + c4);
            o4.x = f2bf(v.x); o4.y = f2bf(v.y); o4.z = f2bf(v.z); o4.w = f2bf(v.w);
        }
        *(short4*)(lH + r * SLDP + c4) = o4;
    }
    __syncthreads();
    // xb out (own rows)
    for (int i = t; i < SROWS * 64; i += 256) {
        int r = i >> 6, c4 = (i & 63) * 4;
        *(short4*)(xb + (size_t)(m0 + r) * HD + c4) =
            *(const short4*)(lH + (r + 7) * SLDP + c4);
    }

    int lane = t & 63, wid = t >> 6;
    int wm = wid & 1, wn = wid >> 1;
    int lm = lane & 15, lk = (lane >> 4) * 8;
    int rbase = (lane >> 4) * 4;

    // ---- pass G1: xb @ Wg_top (A from lH rows +7) ----
    {
        f32x4 accG[2][8] = {};
        for (int kt = 0; kt < 4; ++kt) {
            __syncthreads();
            stage_w(WgT, 512, kt * 64, lB2);
            __syncthreads();
#pragma unroll
            for (int kk2 = 0; kk2 < 64; kk2 += 32) {
                bf16x8 a[2];
#pragma unroll
                for (int i = 0; i < 2; ++i)
                    a[i] = *(const bf16x8*)(lH + (7 + wm * 32 + i * 16 + lm) * SLDP + kt * 64 + kk2 + lk);
#pragma unroll
                for (int j = 0; j < 8; ++j) {
                    bf16x8 b = *(const bf16x8*)(lB2 + (wn * 128 + j * 16 + lm) * LDP + kk2 + lk);
#pragma unroll
                    for (int i = 0; i < 2; ++i)
                        accG[i][j] = __builtin_amdgcn_mfma_f32_16x16x32_bf16(a[i], b, accG[i][j], 0, 0, 0);
                }
            }
        }
#pragma unroll
        for (int i = 0; i < 2; ++i)
#pragma unroll
            for (int j = 0; j < 8; ++j)
#pragma unroll
                for (int r = 0; r < 4; ++r)
                    G1[(size_t)(m0 + wm * 32 + i * 16 + rbase + r) * HD + wn * 128 + j * 16 + lm]
                        = f2bf(accG[i][j][r]);
    }
    __syncthreads();   // all lB2 reads done -> region2 becomes lYZ

    // ---- y = stencil(lH) -> lYZ ----
    {
        int wv = wid, c0 = lane * 4;
        for (int rr = wv; rr < SROWS; rr += 4) {
            float a0 = 0.f, a1 = 0.f, a2 = 0.f, a3 = 0.f;
#pragma unroll
            for (int i = 0; i < 15; ++i) {
                int d = (i < 7) ? (i - 7) : (i - 6);   // -7..-1, 1..8
                float wd = 1.f / (1.f + (float)((d < 0) ? -d : d));
                short4 s4 = *(const short4*)(lH + (rr + 7 + d) * SLDP + c0);
                a0 += wd * bf2f(s4.x); a1 += wd * bf2f(s4.y);
                a2 += wd * bf2f(s4.z); a3 += wd * bf2f(s4.w);
            }
            short4 o;
            o.x = f2bf(a0); o.y = f2bf(a1); o.z = f2bf(a2); o.w = f2bf(a3);
            *(short4*)(lYZ + rr * ZLDP + c0) = o;
        }
    }
    // pass Wc's leading barrier orders: lH reads done before lB1 overwrites,
    // and all y-writes done before A-reads.

    // ---- pass Wc: z = y@Wc + bc + xb ----
    f32x4 acc[2][8] = {};
    for (int kt = 0; kt < 4; ++kt) {
        __syncthreads();
        stage_w(WcT, HD, kt * 64, lB1);
        __syncthreads();
#pragma unroll
        for (int kk2 = 0; kk2 < 64; kk2 += 32) {
            bf16x8 a[2];
#pragma unroll
            for (int i = 0; i < 2; ++i)
                a[i] = *(const bf16x8*)(lYZ + (wm * 32 + i * 16 + lm) * ZLDP + kt * 64 + kk2 + lk);
#pragma unroll
            for (int j = 0; j < 8; ++j) {
                bf16x8 b = *(const bf16x8*)(lB1 + (wn * 128 + j * 16 + lm) * LDP + kk2 + lk);
#pragma unroll
                for (int i = 0; i < 2; ++i)
                    acc[i][j] = __builtin_amdgcn_mfma_f32_16x16x32_bf16(a[i], b, acc[i][j], 0, 0, 0);
            }
        }
    }
    // z + bias + residual, row LN stats
    float zv[2][8][4];
    float s8[2][4] = {}, q8[2][4] = {};
#pragma unroll
    for (int i = 0; i < 2; ++i)
#pragma unroll
        for (int j = 0; j < 8; ++j)
#pragma unroll
            for (int r = 0; r < 4; ++r) {
                int n = wn * 128 + j * 16 + lm;
                int row = m0 + wm * 32 + i * 16 + rbase + r;
                float z = acc[i][j][r] + bc[n] + bf2f(xb[(size_t)row * HD + n]);
                zv[i][j][r] = z; s8[i][r] += z; q8[i][r] += z * z;
            }
#pragma unroll
    for (int i = 0; i < 2; ++i)
#pragma unroll
        for (int r = 0; r < 4; ++r)
#pragma unroll
            for (int o = 1; o < 16; o <<= 1) {
                s8[i][r] += __shfl_xor(s8[i][r], o, 64);
                q8[i][r] += __shfl_xor(q8[i][r], o, 64);
            }
    if (lm == 0)
#pragma unroll
        for (int i = 0; i < 2; ++i)
#pragma unroll
            for (int r = 0; r < 4; ++r) {
                int rowl = wm * 32 + i * 16 + rbase + r;
                red_s[wn * 64 + rowl] = s8[i][r];
                red_q[wn * 64 + rowl] = q8[i][r];
            }
    __syncthreads();
    float mu[2][4], inv[2][4];
#pragma unroll
    for (int i = 0; i < 2; ++i)
#pragma unroll
        for (int r = 0; r < 4; ++r) {
            int rowl = wm * 32 + i * 16 + rbase + r;
            float S = red_s[rowl] + red_s[64 + rowl];
            float Q = red_q[rowl] + red_q[64 + rowl];
            mu[i][r] = S * (1.f / HD);
            inv[i][r] = rsqrtf(Q * (1.f / HD) - mu[i][r] * mu[i][r] + EPSV);
        }
#pragma unroll
    for (int i = 0; i < 2; ++i)
#pragma unroll
        for (int j = 0; j < 8; ++j)
#pragma unroll
            for (int r = 0; r < 4; ++r) {
                int n = wn * 128 + j * 16 + lm;
                int rowl = wm * 32 + i * 16 + rbase + r;
                lYZ[rowl * ZLDP + n] = f2bf((zv[i][j][r] - mu[i][r]) * inv[i][r] * lng[n] + lnb[n]);
            }

    // ---- pass Wa: h = LN(z) @ Wa ----
    f32x4 acc2[2][8] = {};
    for (int kt = 0; kt < 4; ++kt) {
        __syncthreads();
        stage_w(WaT, HD, kt * 64, lB1);
        __syncthreads();
#pragma unroll
        for (int kk2 = 0; kk2 < 64; kk2 += 32) {
            bf16x8 a[2];
#pragma unroll
            for (int i = 0; i < 2; ++i)
                a[i] = *(const bf16x8*)(lYZ + (wm * 32 + i * 16 + lm) * ZLDP + kt * 64 + kk2 + lk);
#pragma unroll
            for (int j = 0; j < 8; ++j) {
                bf16x8 b = *(const bf16x8*)(lB1 + (wn * 128 + j * 16 + lm) * LDP + kk2 + lk);
#pragma unroll
                for (int i = 0; i < 2; ++i)
                    acc2[i][j] = __builtin_amdgcn_mfma_f32_16x16x32_bf16(a[i], b, acc2[i][j], 0, 0, 0);
            }
        }
    }
    float esA[2][4] = {}, etA[2][4] = {}, esB[2][4] = {}, etB[2][4] = {};
#pragma unroll
    for (int j = 0; j < 8; ++j) {
        int n = wn * 128 + j * 16 + lm;
        float as = a_src[n], at = a_tgt[n];
#pragma unroll
        for (int i = 0; i < 2; ++i)
#pragma unroll
            for (int r = 0; r < 4; ++r) {
                int row = m0 + wm * 32 + i * 16 + rbase + r;
                hb[(size_t)row * HD + n] = f2bf(acc2[i][j][r]);
                if (j < 4) { esA[i][r] += acc2[i][j][r] * as; etA[i][r] += acc2[i][j][r] * at; }
                else       { esB[i][r] += acc2[i][j][r] * as; etB[i][r] += acc2[i][j][r] * at; }
            }
    }
#pragma unroll
    for (int i = 0; i < 2; ++i)
#pragma unroll
        for (int r = 0; r < 4; ++r) {
#pragma unroll
            for (int o = 1; o < 16; o <<= 1) {
                esA[i][r] += __shfl_xor(esA[i][r], o, 64);
                etA[i][r] += __shfl_xor(etA[i][r], o, 64);
                esB[i][r] += __shfl_xor(esB[i][r], o, 64);
                etB[i][r] += __shfl_xor(etB[i][r], o, 64);
            }
            if (lm == 0) {
                int row = m0 + wm * 32 + i * 16 + rbase + r;
                es[row * NHEADS + wn * 2 + 0] = esA[i][r];
                et[row * NHEADS + wn * 2 + 0] = etA[i][r];
                es[row * NHEADS + wn * 2 + 1] = esB[i][r];
                et[row * NHEADS + wn * 2 + 1] = etB[i][r];
            }
        }
}

// ---------------------------------------------------------------------------
// Fused tail: block owns 64 rows (XCD-swizzled, grid 256).
//  Phase A: attn + LN -> gs2 in lZ (xb residual from global, coalesced)
//  pass WgBot: accg = gs2@Wg_bot; pass Wp: accp = gs2@Wp
//  epilogue: gate = sigmoid(G1 + accg + bg); out = xb + gate*(accp + bp)
// LDS: region1 41.7K (lH / lB) | lZ 33.8K = 75.5K
// ---------------------------------------------------------------------------
__global__ __launch_bounds__(256) void attn_final(
    const short* __restrict__ hb, const float* __restrict__ es,
    const float* __restrict__ et, const short* __restrict__ xb,
    const short* __restrict__ G1, const float* __restrict__ ba,
    const float* __restrict__ lng, const float* __restrict__ lnb,
    const short* __restrict__ WgT, const float* __restrict__ bg,
    const short* __restrict__ WpT, const float* __restrict__ bp,
    float* __restrict__ out)
{
    __shared__ __align__(16) char smem[75520];
    short* lH = (short*)smem;                // 79 x SLDP (phase A)
    short* lB = (short*)smem;                // 256 x LDP (passes)
    short* lZ = (short*)(smem + 41728);      // 64 x ZLDP

    int t = threadIdx.x;
    int bid = blockIdx.x;
    int swz = (bid & 7) * 32 + (bid >> 3);
    int t0 = swz * SROWS;
    int batch_base = t0 & ~(SEQ - 1);

    for (int i = t; i < (SROWS + SHALO) * 64; i += 256) {
        int r = i >> 6, c4 = (i & 63) * 4;
        int grow = t0 - 7 + r;
        short4 v = {0, 0, 0, 0};
        if (grow >= batch_base && grow < batch_base + SEQ)
            v = *(const short4*)(hb + (size_t)grow * HD + c4);
        *(short4*)(lH + r * SLDP + c4) = v;
    }
    __syncthreads();

    // ---- Phase A: attn + LN -> lZ ----
    int wv = t >> 6, lane = t & 63;
    int tap = lane >> 2, hh = lane & 3;
    int hd = lane >> 4;
    int c0 = lane * 4;
    for (int rr = wv; rr < SROWS; rr += 4) {
        int trow = t0 + rr;
        int p = trow & (SEQ - 1);
        float lg = -1e30f, wd = 0.f;
        bool okk = false;
        if (tap < 15) {
            int d = (tap < 7) ? (tap - 7) : (tap - 6);
            int qp = p + d;
            okk = (qp >= 0) && (qp < SEQ);
            if (okk) {
                float l = es[(trow + d) * NHEADS + hh] + et[trow * NHEADS + hh];
                lg = (l > 0.f) ? l : 0.2f * l;
            }
            wd = 1.f / (1.f + (float)((d < 0) ? -d : d));
        }
        float m = lg;
#pragma unroll
        for (int o = 4; o < 64; o <<= 1) m = fmaxf(m, __shfl_xor(m, o, 64));
        float un = okk ? __expf(lg - m) * wd : 0.f;
        float den = un;
#pragma unroll
        for (int o = 4; o < 64; o <<= 1) den += __shfl_xor(den, o, 64);
        float alpha_l = un / (den + 1e-9f);

        float al[15];
#pragma unroll
        for (int i = 0; i < 15; ++i) al[i] = __shfl(alpha_l, i * 4 + hd, 64);

        float a0 = 0.f, a1 = 0.f, a2 = 0.f, a3 = 0.f;
#pragma unroll
        for (int i = 0; i < 15; ++i) {
            int d = (i < 7) ? (i - 7) : (i - 6);
            short4 s4 = *(const short4*)(lH + (rr + 7 + d) * SLDP + c0);
            a0 += al[i] * bf2f(s4.x); a1 += al[i] * bf2f(s4.y);
            a2 += al[i] * bf2f(s4.z); a3 += al[i] * bf2f(s4.w);
        }
        short4 xv4 = *(const short4*)(xb + (size_t)trow * HD + c0);
        float4 bav = *(const float4*)(ba + c0);
        float v0 = a0 + bav.x + bf2f(xv4.x), v1 = a1 + bav.y + bf2f(xv4.y);
        float v2 = a2 + bav.z + bf2f(xv4.z), v3 = a3 + bav.w + bf2f(xv4.w);
        float s = v0 + v1 + v2 + v3;
        float q = v0 * v0 + v1 * v1 + v2 * v2 + v3 * v3;
#pragma unroll
        for (int o = 1; o < 64; o <<= 1) { s += __shfl_xor(s, o, 64); q += __shfl_xor(q, o, 64); }
        float mu = s * (1.f / HD);
        float var = q * (1.f / HD) - mu * mu;
        float inv = rsqrtf(var + EPSV);
        float4 gv = *(const float4*)(lng + c0);
        float4 bv = *(const float4*)(lnb + c0);
        short4 o4;
        o4.x = f2bf((v0 - mu) * inv * gv.x + bv.x);
        o4.y = f2bf((v1 - mu) * inv * gv.y + bv.y);
        o4.z = f2bf((v2 - mu) * inv * gv.z + bv.z);
        o4.w = f2bf((v3 - mu) * inv * gv.w + bv.w);
        *(short4*)(lZ + rr * ZLDP + c0) = o4;
    }
    // pass WgBot's leading barrier orders lH reads before lB writes & lZ ready.

    int wid = t >> 6;
    int wm = wid & 1, wn = wid >> 1;
    int lm = lane & 15, lk = (lane >> 4) * 8;
    int rbase = (lane >> 4) * 4;
    f32x4 accg[2][8] = {}, accp[2][8] = {};
    for (int kt = 0; kt < 4; ++kt) {
        __syncthreads();
        stage_w(WgT, 512, 256 + kt * 64, lB);
        __syncthreads();
#pragma unroll
        for (int kk2 = 0; kk2 < 64; kk2 += 32) {
            bf16x8 a[2];
#pragma unroll
            for (int i = 0; i < 2; ++i)
                a[i] = *(const bf16x8*)(lZ + (wm * 32 + i * 16 + lm) * ZLDP + kt * 64 + kk2 + lk);
#pragma unroll
            for (int j = 0; j < 8; ++j) {
                bf16x8 b = *(const bf16x8*)(lB + (wn * 128 + j * 16 + lm) * LDP + kk2 + lk);
#pragma unroll
                for (int i = 0; i < 2; ++i)
                    accg[i][j] = __builtin_amdgcn_mfma_f32_16x16x32_bf16(a[i], b, accg[i][j], 0, 0, 0);
            }
        }
    }
    for (int kt = 0; kt < 4; ++kt) {
        __syncthreads();
        stage_w(WpT, HD, kt * 64, lB);
        __syncthreads();
#pragma unroll
        for (int kk2 = 0; kk2 < 64; kk2 += 32) {
            bf16x8 a[2];
#pragma unroll
            for (int i = 0; i < 2; ++i)
                a[i] = *(const bf16x8*)(lZ + (wm * 32 + i * 16 + lm) * ZLDP + kt * 64 + kk2 + lk);
#pragma unroll
            for (int j = 0; j < 8; ++j) {
                bf16x8 b = *(const bf16x8*)(lB + (wn * 128 + j * 16 + lm) * LDP + kk2 + lk);
#pragma unroll
                for (int i = 0; i < 2; ++i)
                    accp[i][j] = __builtin_amdgcn_mfma_f32_16x16x32_bf16(a[i], b, accp[i][j], 0, 0, 0);
            }
        }
    }
#pragma unroll
    for (int i = 0; i < 2; ++i)
#pragma unroll
        for (int j = 0; j < 8; ++j)
#pragma unroll
            for (int r = 0; r < 4; ++r) {
                int n = wn * 128 + j * 16 + lm;
                size_t m = (size_t)(t0 + wm * 32 + i * 16 + rbase + r);
                float g1 = bf2f(G1[m * HD + n]);
                float gate = 1.f / (1.f + __expf(-(accg[i][j][r] + g1 + bg[n])));
                float pv = accp[i][j][r] + bp[n];
                out[m * HD + n] = bf2f(xb[m * HD + n]) + gate * pv;
            }
}

// ---------------------------------------------------------------------------
extern "C" void kernel_launch(void* const* d_in, const int* in_sizes, int n_in,
                              void* d_out, int out_size, void* d_ws, size_t ws_size,
                              hipStream_t stream)
{
    const float* x     = (const float*)d_in[0];
    const float* Wc    = (const float*)d_in[1];
    const float* bc    = (const float*)d_in[2];
    const float* Wa    = (const float*)d_in[3];
    const float* a_src = (const float*)d_in[4];
    const float* a_tgt = (const float*)d_in[5];
    const float* ba    = (const float*)d_in[6];
    const float* ln_g  = (const float*)d_in[7];
    const float* ln_b  = (const float*)d_in[8];
    const float* Wg    = (const float*)d_in[9];
    const float* bg    = (const float*)d_in[10];
    const float* Wp    = (const float*)d_in[11];
    const float* bp    = (const float*)d_in[12];

    float* out = (float*)d_out;      // written only by attn_final epilogue

    char* w = (char*)d_ws;
    short* xb  = (short*)w;   w += (size_t)NR * HD * 2;   // bf16 x
    short* hb  = (short*)w;   w += (size_t)NR * HD * 2;   // h bf16
    short* G1  = (short*)w;   w += (size_t)NR * HD * 2;   // xb@Wg_top bf16
    float* es  = (float*)w;   w += (size_t)NR * NHEADS * 4;
    float* et  = (float*)w;   w += (size_t)NR * NHEADS * 4;
    short* WcT = (short*)w;   w += 256 * 256 * 2;
    short* WaT = (short*)w;   w += 256 * 256 * 2;
    short* WpT = (short*)w;   w += 256 * 256 * 2;
    short* WgT = (short*)w;   w += 512 * 256 * 2;

    // 0) weights^T (tiny)
    prep_w<<<dim3(32, 4), 256, 0, stream>>>(Wc, Wa, Wg, Wp, WcT, WaT, WgT, WpT);
    // 1) stencil -> G1 = xb@Wg_top -> z=y@Wc+bc+xb -> LN -> h=LN(z)@Wa -> es/et
    stencil_gemm<<<NR / SROWS, 256, 0, stream>>>(x, WcT, bc, WaT, WgT, ln_g, ln_b,
                                                 a_src, a_tgt, xb, hb, G1, es, et);
    // 2) gs2 = LN(attn(h)+ba+xb) in LDS -> out = xb + sigmoid(G1+gs2@WgBot+bg)*(gs2@Wp+bp)
    attn_final<<<NR / SROWS, 256, 0, stream>>>(hb, es, et, xb, G1, ba, ln_g, ln_b,
                                               WgT, bg, WpT, bp, out);
}

// Round 14
// 92.989 us; speedup vs baseline: 1.2086x; 1.2086x over previous
//
#include <hip/hip_runtime.h>
#include <math.h>

#define HD 256
#define SEQ 4096
#define NR 16384
#define NHEADS 4
#define EPSV 1e-5f
#define LDP 72    // padded LDS row stride for GEMM K-tiles
#define ZLDP 264  // padded LDS row stride for 256-wide row tiles
#define SROWS 32  // rows per block
#define SHALO 15  // 7 below + 8 above
#define SLDP 264  // halo-tile LDS row stride

typedef __attribute__((ext_vector_type(8))) short bf16x8;
typedef __attribute__((ext_vector_type(4))) float f32x4;

__device__ inline short f2bf(float f) {
    unsigned u = __float_as_uint(f);
    u += 0x7FFF + ((u >> 16) & 1);     // round-to-nearest-even
    return (short)(u >> 16);
}
__device__ inline float bf2f(short s) {
    return __uint_as_float(((unsigned)(unsigned short)s) << 16);
}

// Stage a [256 x 64] bf16 weight tile into padded LDS. Coalesced 16B chunks.
__device__ inline void stage_w(const short* __restrict__ src, int src_stride,
                               int k0, short* lds)
{
    int t = threadIdx.x;
#pragma unroll
    for (int c = 0; c < 8; ++c) {
        int idx = c * 256 + t;
        int r = idx >> 3, kg = idx & 7;
        bf16x8 v = *(const bf16x8*)(src + (size_t)r * src_stride + k0 + kg * 8);
        *(bf16x8*)(lds + r * LDP + kg * 8) = v;
    }
}

// ---------------------------------------------------------------------------
// Merged prep + stencil. grid (512, 5):
//  task 0: stencil+cast: xb = bf16(x), y = 15-tap stencil(x)
//  tasks 1-4: weight transpose+cast (Wc/Wa/Wg/Wp)
// ---------------------------------------------------------------------------
__global__ __launch_bounds__(256) void prep_stencil(
    const float* __restrict__ x,
    const float* __restrict__ Wc, const float* __restrict__ Wa,
    const float* __restrict__ Wg, const float* __restrict__ Wp,
    short* __restrict__ xb, short* __restrict__ y,
    short* __restrict__ WcT, short* __restrict__ WaT,
    short* __restrict__ WgT, short* __restrict__ WpT)
{
    __shared__ __align__(16) char smem[(SROWS + SHALO) * SLDP * 2];
    int task = blockIdx.y;
    int bx = blockIdx.x;
    int t = threadIdx.x;

    if (task == 0) {                   // stencil + cast
        short* lH = (short*)smem;
        int t0 = bx * SROWS;
        int batch_base = t0 & ~(SEQ - 1);
        for (int i = t; i < (SROWS + SHALO) * 64; i += 256) {
            int r = i >> 6, c4 = (i & 63) * 4;
            int grow = t0 - 7 + r;
            short4 o4 = {0, 0, 0, 0};
            if (grow >= batch_base && grow < batch_base + SEQ) {
                float4 v = *(const float4*)(x + (size_t)grow * HD + c4);
                o4.x = f2bf(v.x); o4.y = f2bf(v.y); o4.z = f2bf(v.z); o4.w = f2bf(v.w);
            }
            *(short4*)(lH + r * SLDP + c4) = o4;
        }
        __syncthreads();
        for (int i = t; i < SROWS * 64; i += 256) {
            int r = i >> 6, c4 = (i & 63) * 4;
            *(short4*)(xb + (size_t)(t0 + r) * HD + c4) =
                *(const short4*)(lH + (r + 7) * SLDP + c4);
        }
        int wv = t >> 6, lane = t & 63;
        int c0 = lane * 4;
        for (int rr = wv; rr < SROWS; rr += 4) {
            float a0 = 0.f, a1 = 0.f, a2 = 0.f, a3 = 0.f;
#pragma unroll
            for (int i = 0; i < 15; ++i) {
                int d = (i < 7) ? (i - 7) : (i - 6);   // -7..-1, 1..8
                float wd = 1.f / (1.f + (float)((d < 0) ? -d : d));
                short4 s4 = *(const short4*)(lH + (rr + 7 + d) * SLDP + c0);
                a0 += wd * bf2f(s4.x); a1 += wd * bf2f(s4.y);
                a2 += wd * bf2f(s4.z); a3 += wd * bf2f(s4.w);
            }
            short4 o;
            o.x = f2bf(a0); o.y = f2bf(a1); o.z = f2bf(a2); o.w = f2bf(a3);
            *(short4*)(y + (size_t)(t0 + rr) * HD + c0) = o;
        }
        return;
    }
    // tasks 1-4: W^T via LDS tile (64x64)
    float (*lds)[65] = (float (*)[65])smem;
    const float* W; short* Wt; int K;
    if (task == 1)      { W = Wc; Wt = WcT; K = 256; }
    else if (task == 2) { W = Wa; Wt = WaT; K = 256; }
    else if (task == 3) { W = Wg; Wt = WgT; K = 512; }
    else                { W = Wp; Wt = WpT; K = 256; }
    int ntiles = (K >> 6) * 4;
    if (bx >= ntiles) return;
    int k0 = (bx >> 2) * 64, n0 = (bx & 3) * 64;
    int ty = t >> 6, tx = t & 63;
#pragma unroll
    for (int s = 0; s < 16; ++s) {
        int r = s * 4 + ty;
        lds[r][tx] = W[(size_t)(k0 + r) * 256 + n0 + tx];
    }
    __syncthreads();
#pragma unroll
    for (int s = 0; s < 16; ++s) {
        int rn = s * 4 + ty;
        Wt[(size_t)(n0 + rn) * K + k0 + tx] = f2bf(lds[tx][rn]);
    }
}

// ---------------------------------------------------------------------------
// Fused middle: block owns 32 rows (XCD-swizzled, grid 512).
//  y staged ONCE into lZ; Phase 1: z = y@Wc + bc + xb -> LN(z) overwrites lZ
//  Phase 2: h = LN(z)@Wa -> global; es/et (wave-local)
// LDS: lB 36.9K | lZ 16.9K | red 0.5K = 54.3K -> 3 blocks/CU
// ---------------------------------------------------------------------------
__global__ __launch_bounds__(256) void gemm_fused(
    const short* __restrict__ y, const short* __restrict__ WcT,
    const short* __restrict__ xb, const float* __restrict__ bc,
    const short* __restrict__ WaT,
    const float* __restrict__ lng, const float* __restrict__ lnb,
    const float* __restrict__ a_src, const float* __restrict__ a_tgt,
    short* __restrict__ hb, float* __restrict__ es, float* __restrict__ et)
{
    __shared__ __align__(16) short lB[256 * LDP];   // 36864B
    __shared__ __align__(16) short lZ[32 * ZLDP];   // 16896B (y, then LN(z))
    __shared__ float red_s[64], red_q[64];          // [2][32]
    int t = threadIdx.x;
    int bid = blockIdx.x;
    int swz = (bid & 7) * 64 + (bid >> 3);
    int m0 = swz * SROWS;
    int lane = t & 63, wid = t >> 6;
    int wm = wid & 1, wn = wid >> 1;
    int lm = lane & 15, lk = (lane >> 4) * 8;
    int rbase = (lane >> 4) * 4;

    // stage full y tile (32 x 256) into lZ once
#pragma unroll
    for (int c = 0; c < 4; ++c) {
        int idx = c * 256 + t;
        int r = idx >> 5, kg = idx & 31;
        *(bf16x8*)(lZ + r * ZLDP + kg * 8) =
            *(const bf16x8*)(y + (size_t)(m0 + r) * HD + kg * 8);
    }

    // ---- Phase 1: z = y@Wc ----
    f32x4 acc[8] = {};
    for (int kt = 0; kt < 4; ++kt) {
        __syncthreads();
        stage_w(WcT, HD, kt * 64, lB);
        __syncthreads();
#pragma unroll
        for (int kk2 = 0; kk2 < 64; kk2 += 32) {
            bf16x8 a = *(const bf16x8*)(lZ + (wm * 16 + lm) * ZLDP + kt * 64 + kk2 + lk);
#pragma unroll
            for (int j = 0; j < 8; ++j) {
                bf16x8 b = *(const bf16x8*)(lB + (wn * 128 + j * 16 + lm) * LDP + kk2 + lk);
                acc[j] = __builtin_amdgcn_mfma_f32_16x16x32_bf16(a, b, acc[j], 0, 0, 0);
            }
        }
    }
    float zv[8][4];
    float s4r[4] = {}, q4r[4] = {};
#pragma unroll
    for (int j = 0; j < 8; ++j)
#pragma unroll
        for (int r = 0; r < 4; ++r) {
            int n = wn * 128 + j * 16 + lm;
            int row = m0 + wm * 16 + rbase + r;
            float z = acc[j][r] + bc[n] + bf2f(xb[(size_t)row * HD + n]);
            zv[j][r] = z; s4r[r] += z; q4r[r] += z * z;
        }
#pragma unroll
    for (int r = 0; r < 4; ++r)
#pragma unroll
        for (int o = 1; o < 16; o <<= 1) {
            s4r[r] += __shfl_xor(s4r[r], o, 64);
            q4r[r] += __shfl_xor(q4r[r], o, 64);
        }
    if (lm == 0)
#pragma unroll
        for (int r = 0; r < 4; ++r) {
            red_s[wn * 32 + wm * 16 + rbase + r] = s4r[r];
            red_q[wn * 32 + wm * 16 + rbase + r] = q4r[r];
        }
    __syncthreads();   // also orders: all phase-1 lZ reads done before overwrite
    float mu[4], inv[4];
#pragma unroll
    for (int r = 0; r < 4; ++r) {
        int rowl = wm * 16 + rbase + r;
        float S = red_s[rowl] + red_s[32 + rowl];
        float Q = red_q[rowl] + red_q[32 + rowl];
        mu[r] = S * (1.f / HD);
        inv[r] = rsqrtf(Q * (1.f / HD) - mu[r] * mu[r] + EPSV);
    }
#pragma unroll
    for (int j = 0; j < 8; ++j)
#pragma unroll
        for (int r = 0; r < 4; ++r) {
            int n = wn * 128 + j * 16 + lm;
            int rowl = wm * 16 + rbase + r;
            lZ[rowl * ZLDP + n] = f2bf((zv[j][r] - mu[r]) * inv[r] * lng[n] + lnb[n]);
        }

    // ---- Phase 2: h = LN(z) @ Wa ----
    f32x4 acc2[8] = {};
    for (int kt = 0; kt < 4; ++kt) {
        __syncthreads();
        stage_w(WaT, HD, kt * 64, lB);
        __syncthreads();
#pragma unroll
        for (int kk2 = 0; kk2 < 64; kk2 += 32) {
            bf16x8 a = *(const bf16x8*)(lZ + (wm * 16 + lm) * ZLDP + kt * 64 + kk2 + lk);
#pragma unroll
            for (int j = 0; j < 8; ++j) {
                bf16x8 b = *(const bf16x8*)(lB + (wn * 128 + j * 16 + lm) * LDP + kk2 + lk);
                acc2[j] = __builtin_amdgcn_mfma_f32_16x16x32_bf16(a, b, acc2[j], 0, 0, 0);
            }
        }
    }
    float esA[4] = {}, etA[4] = {}, esB[4] = {}, etB[4] = {};
#pragma unroll
    for (int j = 0; j < 8; ++j) {
        int n = wn * 128 + j * 16 + lm;
        float as = a_src[n], at = a_tgt[n];
#pragma unroll
        for (int r = 0; r < 4; ++r) {
            int row = m0 + wm * 16 + rbase + r;
            hb[(size_t)row * HD + n] = f2bf(acc2[j][r]);
            if (j < 4) { esA[r] += acc2[j][r] * as; etA[r] += acc2[j][r] * at; }
            else       { esB[r] += acc2[j][r] * as; etB[r] += acc2[j][r] * at; }
        }
    }
#pragma unroll
    for (int r = 0; r < 4; ++r) {
#pragma unroll
        for (int o = 1; o < 16; o <<= 1) {
            esA[r] += __shfl_xor(esA[r], o, 64);
            etA[r] += __shfl_xor(etA[r], o, 64);
            esB[r] += __shfl_xor(esB[r], o, 64);
            etB[r] += __shfl_xor(etB[r], o, 64);
        }
        if (lm == 0) {
            int row = m0 + wm * 16 + rbase + r;
            es[row * NHEADS + wn * 2 + 0] = esA[r];
            et[row * NHEADS + wn * 2 + 0] = etA[r];
            es[row * NHEADS + wn * 2 + 1] = esB[r];
            et[row * NHEADS + wn * 2 + 1] = etB[r];
        }
    }
}

// ---------------------------------------------------------------------------
// Fused tail: block owns 32 rows (XCD-swizzled, grid 512).
//  Phase A: attn + LN -> gs2 in lZ (xb residual from global)
//  Pass 1: accg = xb@Wg_top (A frags global-direct, L2-hot)
//  Pass 2: accg += gs2@Wg_bot; Pass 3: accp = gs2@Wp
//  epilogue: out = xb + sigmoid(accg+bg)*(accp+bp)
// LDS: union(lH 24.8K, lB 36.9K) + lZ 16.9K = 53.76K -> 3 blocks/CU
// ---------------------------------------------------------------------------
__global__ __launch_bounds__(256) void attn_final(
    const short* __restrict__ hb, const float* __restrict__ es,
    const float* __restrict__ et, const short* __restrict__ xb,
    const float* __restrict__ ba, const float* __restrict__ lng,
    const float* __restrict__ lnb,
    const short* __restrict__ WgT, const float* __restrict__ bg,
    const short* __restrict__ WpT, const float* __restrict__ bp,
    float* __restrict__ out)
{
    __shared__ __align__(16) char smem[256 * LDP * 2 + 32 * ZLDP * 2];
    short* lH = (short*)smem;                       // 47 x SLDP (phase A)
    short* lB = (short*)smem;                       // 256 x LDP (passes)
    short* lZ = (short*)(smem + 256 * LDP * 2);     // gs2, 32 x ZLDP

    int t = threadIdx.x;
    int bid = blockIdx.x;
    int swz = (bid & 7) * 64 + (bid >> 3);
    int t0 = swz * SROWS;
    int batch_base = t0 & ~(SEQ - 1);

    for (int i = t; i < (SROWS + SHALO) * 64; i += 256) {
        int r = i >> 6, c4 = (i & 63) * 4;
        int grow = t0 - 7 + r;
        short4 v = {0, 0, 0, 0};
        if (grow >= batch_base && grow < batch_base + SEQ)
            v = *(const short4*)(hb + (size_t)grow * HD + c4);
        *(short4*)(lH + r * SLDP + c4) = v;
    }
    __syncthreads();

    // ---- Phase A: attn + LN -> lZ ----
    int wv = t >> 6, lane = t & 63;
    int tap = lane >> 2, hh = lane & 3;
    int hd = lane >> 4;
    int c0 = lane * 4;
    for (int rr = wv; rr < SROWS; rr += 4) {
        int trow = t0 + rr;
        int p = trow & (SEQ - 1);
        float lg = -1e30f, wd = 0.f;
        bool okk = false;
        if (tap < 15) {
            int d = (tap < 7) ? (tap - 7) : (tap - 6);
            int qp = p + d;
            okk = (qp >= 0) && (qp < SEQ);
            if (okk) {
                float l = es[(trow + d) * NHEADS + hh] + et[trow * NHEADS + hh];
                lg = (l > 0.f) ? l : 0.2f * l;
            }
            wd = 1.f / (1.f + (float)((d < 0) ? -d : d));
        }
        float m = lg;
#pragma unroll
        for (int o = 4; o < 64; o <<= 1) m = fmaxf(m, __shfl_xor(m, o, 64));
        float un = okk ? __expf(lg - m) * wd : 0.f;
        float den = un;
#pragma unroll
        for (int o = 4; o < 64; o <<= 1) den += __shfl_xor(den, o, 64);
        float alpha_l = un / (den + 1e-9f);

        float al[15];
#pragma unroll
        for (int i = 0; i < 15; ++i) al[i] = __shfl(alpha_l, i * 4 + hd, 64);

        float a0 = 0.f, a1 = 0.f, a2 = 0.f, a3 = 0.f;
#pragma unroll
        for (int i = 0; i < 15; ++i) {
            int d = (i < 7) ? (i - 7) : (i - 6);
            short4 s4 = *(const short4*)(lH + (rr + 7 + d) * SLDP + c0);
            a0 += al[i] * bf2f(s4.x); a1 += al[i] * bf2f(s4.y);
            a2 += al[i] * bf2f(s4.z); a3 += al[i] * bf2f(s4.w);
        }
        short4 xv4 = *(const short4*)(xb + (size_t)trow * HD + c0);
        float4 bav = *(const float4*)(ba + c0);
        float v0 = a0 + bav.x + bf2f(xv4.x), v1 = a1 + bav.y + bf2f(xv4.y);
        float v2 = a2 + bav.z + bf2f(xv4.z), v3 = a3 + bav.w + bf2f(xv4.w);
        float s = v0 + v1 + v2 + v3;
        float q = v0 * v0 + v1 * v1 + v2 * v2 + v3 * v3;
#pragma unroll
        for (int o = 1; o < 64; o <<= 1) { s += __shfl_xor(s, o, 64); q += __shfl_xor(q, o, 64); }
        float mu = s * (1.f / HD);
        float var = q * (1.f / HD) - mu * mu;
        float inv = rsqrtf(var + EPSV);
        float4 gv = *(const float4*)(lng + c0);
        float4 bv = *(const float4*)(lnb + c0);
        short4 o4;
        o4.x = f2bf((v0 - mu) * inv * gv.x + bv.x);
        o4.y = f2bf((v1 - mu) * inv * gv.y + bv.y);
        o4.z = f2bf((v2 - mu) * inv * gv.z + bv.z);
        o4.w = f2bf((v3 - mu) * inv * gv.w + bv.w);
        *(short4*)(lZ + rr * ZLDP + c0) = o4;
    }
    // pass 1's leading barrier orders lH reads before lB overwrite & lZ ready

    int wid = t >> 6;
    int wm = wid & 1, wn = wid >> 1;
    int lm = lane & 15, lk = (lane >> 4) * 8;
    int rbase = (lane >> 4) * 4;
    f32x4 accg[8] = {}, accp[8] = {};
    // Pass 1: xb @ Wg_top (A frags direct from global, L2-hot)
    for (int kt = 0; kt < 4; ++kt) {
        __syncthreads();
        stage_w(WgT, 512, kt * 64, lB);
        __syncthreads();
#pragma unroll
        for (int kk2 = 0; kk2 < 64; kk2 += 32) {
            bf16x8 a = *(const bf16x8*)(xb + (size_t)(t0 + wm * 16 + lm) * HD + kt * 64 + kk2 + lk);
#pragma unroll
            for (int j = 0; j < 8; ++j) {
                bf16x8 b = *(const bf16x8*)(lB + (wn * 128 + j * 16 + lm) * LDP + kk2 + lk);
                accg[j] = __builtin_amdgcn_mfma_f32_16x16x32_bf16(a, b, accg[j], 0, 0, 0);
            }
        }
    }
    // Pass 2: += gs2 @ Wg_bot
    for (int kt = 0; kt < 4; ++kt) {
        __syncthreads();
        stage_w(WgT, 512, 256 + kt * 64, lB);
        __syncthreads();
#pragma unroll
        for (int kk2 = 0; kk2 < 64; kk2 += 32) {
            bf16x8 a = *(const bf16x8*)(lZ + (wm * 16 + lm) * ZLDP + kt * 64 + kk2 + lk);
#pragma unroll
            for (int j = 0; j < 8; ++j) {
                bf16x8 b = *(const bf16x8*)(lB + (wn * 128 + j * 16 + lm) * LDP + kk2 + lk);
                accg[j] = __builtin_amdgcn_mfma_f32_16x16x32_bf16(a, b, accg[j], 0, 0, 0);
            }
        }
    }
    // Pass 3: accp = gs2 @ Wp
    for (int kt = 0; kt < 4; ++kt) {
        __syncthreads();
        stage_w(WpT, HD, kt * 64, lB);
        __syncthreads();
#pragma unroll
        for (int kk2 = 0; kk2 < 64; kk2 += 32) {
            bf16x8 a = *(const bf16x8*)(lZ + (wm * 16 + lm) * ZLDP + kt * 64 + kk2 + lk);
#pragma unroll
            for (int j = 0; j < 8; ++j) {
                bf16x8 b = *(const bf16x8*)(lB + (wn * 128 + j * 16 + lm) * LDP + kk2 + lk);
                accp[j] = __builtin_amdgcn_mfma_f32_16x16x32_bf16(a, b, accp[j], 0, 0, 0);
            }
        }
    }
#pragma unroll
    for (int j = 0; j < 8; ++j)
#pragma unroll
        for (int r = 0; r < 4; ++r) {
            int n = wn * 128 + j * 16 + lm;
            size_t m = (size_t)(t0 + wm * 16 + rbase + r);
            float gate = 1.f / (1.f + __expf(-(accg[j][r] + bg[n])));
            float pv = accp[j][r] + bp[n];
            out[m * HD + n] = bf2f(xb[m * HD + n]) + gate * pv;
        }
}

// ---------------------------------------------------------------------------
extern "C" void kernel_launch(void* const* d_in, const int* in_sizes, int n_in,
                              void* d_out, int out_size, void* d_ws, size_t ws_size,
                              hipStream_t stream)
{
    const float* x     = (const float*)d_in[0];
    const float* Wc    = (const float*)d_in[1];
    const float* bc    = (const float*)d_in[2];
    const float* Wa    = (const float*)d_in[3];
    const float* a_src = (const float*)d_in[4];
    const float* a_tgt = (const float*)d_in[5];
    const float* ba    = (const float*)d_in[6];
    const float* ln_g  = (const float*)d_in[7];
    const float* ln_b  = (const float*)d_in[8];
    const float* Wg    = (const float*)d_in[9];
    const float* bg    = (const float*)d_in[10];
    const float* Wp    = (const float*)d_in[11];
    const float* bp    = (const float*)d_in[12];

    float* out = (float*)d_out;      // written only by attn_final

    char* w = (char*)d_ws;
    short* y   = (short*)w;   w += (size_t)NR * HD * 2;   // stencil(x) bf16
    short* xb  = (short*)w;   w += (size_t)NR * HD * 2;   // bf16 x
    short* hb  = (short*)w;   w += (size_t)NR * HD * 2;   // h bf16
    float* es  = (float*)w;   w += (size_t)NR * NHEADS * 4;
    float* et  = (float*)w;   w += (size_t)NR * NHEADS * 4;
    short* WcT = (short*)w;   w += 256 * 256 * 2;
    short* WaT = (short*)w;   w += 256 * 256 * 2;
    short* WpT = (short*)w;   w += 256 * 256 * 2;
    short* WgT = (short*)w;   w += 512 * 256 * 2;

    // 0) merged: stencil+cast / weights^T
    prep_stencil<<<dim3(NR / SROWS, 5), 256, 0, stream>>>(
        x, Wc, Wa, Wg, Wp, xb, y, WcT, WaT, WgT, WpT);
    // 1) fused: z=y@Wc+bc+xb -> LN -> h=LN(z)@Wa -> es/et   (z stays in LDS)
    gemm_fused<<<NR / SROWS, 256, 0, stream>>>(y, WcT, xb, bc, WaT, ln_g, ln_b,
                                               a_src, a_tgt, hb, es, et);
    // 2) fused: gs2 = LN(attn(h)+ba+xb) in LDS -> out = xb + gate*(gs2@Wp+bp)
    attn_final<<<NR / SROWS, 256, 0, stream>>>(hb, es, et, xb, ba, ln_g, ln_b,
                                               WgT, bg, WpT, bp, out);
}

// Round 15
// 67.542 us; speedup vs baseline: 1.6640x; 1.3768x over previous
//
#include <hip/hip_runtime.h>
#include <math.h>

#define HD 256
#define SEQ 4096
#define NR 16384
#define NHEADS 4
#define EPSV 1e-5f
#define LDP 72    // padded LDS row stride for GEMM K-tiles
#define ZLDP 264  // padded LDS row stride for 256-wide row tiles
#define SROWS 32  // rows per block
#define SHALO 15  // 7 below + 8 above
#define SLDP 264  // halo-tile LDS row stride

typedef __attribute__((ext_vector_type(8))) short bf16x8;
typedef __attribute__((ext_vector_type(4))) float f32x4;

__device__ inline short f2bf(float f) {
    unsigned u = __float_as_uint(f);
    u += 0x7FFF + ((u >> 16) & 1);     // round-to-nearest-even
    return (short)(u >> 16);
}
__device__ inline float bf2f(short s) {
    return __uint_as_float(((unsigned)(unsigned short)s) << 16);
}

// Stage a [256 x 64] bf16 weight tile into padded LDS. Coalesced 16B chunks.
__device__ inline void stage_w(const short* __restrict__ src, int src_stride,
                               int k0, short* lds)
{
    int t = threadIdx.x;
#pragma unroll
    for (int c = 0; c < 8; ++c) {
        int idx = c * 256 + t;
        int r = idx >> 3, kg = idx & 7;
        bf16x8 v = *(const bf16x8*)(src + (size_t)r * src_stride + k0 + kg * 8);
        *(bf16x8*)(lds + r * LDP + kg * 8) = v;
    }
}

// ---------------------------------------------------------------------------
// Merged prep + stencil. grid (512, 5):
//  task 0: stencil+cast: xb = bf16(x), y = 15-tap stencil(x)
//  tasks 1-4: weight transpose+cast (Wc/Wa/Wg/Wp)
// ---------------------------------------------------------------------------
__global__ __launch_bounds__(256) void prep_stencil(
    const float* __restrict__ x,
    const float* __restrict__ Wc, const float* __restrict__ Wa,
    const float* __restrict__ Wg, const float* __restrict__ Wp,
    short* __restrict__ xb, short* __restrict__ y,
    short* __restrict__ WcT, short* __restrict__ WaT,
    short* __restrict__ WgT, short* __restrict__ WpT)
{
    __shared__ __align__(16) char smem[(SROWS + SHALO) * SLDP * 2];
    int task = blockIdx.y;
    int bx = blockIdx.x;
    int t = threadIdx.x;

    if (task == 0) {                   // stencil + cast
        short* lH = (short*)smem;
        int t0 = bx * SROWS;
        int batch_base = t0 & ~(SEQ - 1);
        for (int i = t; i < (SROWS + SHALO) * 64; i += 256) {
            int r = i >> 6, c4 = (i & 63) * 4;
            int grow = t0 - 7 + r;
            short4 o4 = {0, 0, 0, 0};
            if (grow >= batch_base && grow < batch_base + SEQ) {
                float4 v = *(const float4*)(x + (size_t)grow * HD + c4);
                o4.x = f2bf(v.x); o4.y = f2bf(v.y); o4.z = f2bf(v.z); o4.w = f2bf(v.w);
            }
            *(short4*)(lH + r * SLDP + c4) = o4;
        }
        __syncthreads();
        for (int i = t; i < SROWS * 64; i += 256) {
            int r = i >> 6, c4 = (i & 63) * 4;
            *(short4*)(xb + (size_t)(t0 + r) * HD + c4) =
                *(const short4*)(lH + (r + 7) * SLDP + c4);
        }
        int wv = t >> 6, lane = t & 63;
        int c0 = lane * 4;
        for (int rr = wv; rr < SROWS; rr += 4) {
            float a0 = 0.f, a1 = 0.f, a2 = 0.f, a3 = 0.f;
#pragma unroll
            for (int i = 0; i < 15; ++i) {
                int d = (i < 7) ? (i - 7) : (i - 6);   // -7..-1, 1..8
                float wd = 1.f / (1.f + (float)((d < 0) ? -d : d));
                short4 s4 = *(const short4*)(lH + (rr + 7 + d) * SLDP + c0);
                a0 += wd * bf2f(s4.x); a1 += wd * bf2f(s4.y);
                a2 += wd * bf2f(s4.z); a3 += wd * bf2f(s4.w);
            }
            short4 o;
            o.x = f2bf(a0); o.y = f2bf(a1); o.z = f2bf(a2); o.w = f2bf(a3);
            *(short4*)(y + (size_t)(t0 + rr) * HD + c0) = o;
        }
        return;
    }
    // tasks 1-4: W^T via LDS tile (64x64)
    float (*lds)[65] = (float (*)[65])smem;
    const float* W; short* Wt; int K;
    if (task == 1)      { W = Wc; Wt = WcT; K = 256; }
    else if (task == 2) { W = Wa; Wt = WaT; K = 256; }
    else if (task == 3) { W = Wg; Wt = WgT; K = 512; }
    else                { W = Wp; Wt = WpT; K = 256; }
    int ntiles = (K >> 6) * 4;
    if (bx >= ntiles) return;
    int k0 = (bx >> 2) * 64, n0 = (bx & 3) * 64;
    int ty = t >> 6, tx = t & 63;
#pragma unroll
    for (int s = 0; s < 16; ++s) {
        int r = s * 4 + ty;
        lds[r][tx] = W[(size_t)(k0 + r) * 256 + n0 + tx];
    }
    __syncthreads();
#pragma unroll
    for (int s = 0; s < 16; ++s) {
        int rn = s * 4 + ty;
        Wt[(size_t)(n0 + rn) * K + k0 + tx] = f2bf(lds[tx][rn]);
    }
}

// ---------------------------------------------------------------------------
// Fused middle: block owns 32 rows (grid 512).
//  y staged ONCE into lZ; Phase 1: z = y@Wc + bc + xb -> LN(z) overwrites lZ
//  Phase 2: h = LN(z)@Wa -> global; es/et (wave-local)
// LDS: lB 36.9K | lZ 16.9K | red 0.5K = 54.3K -> 3 blocks/CU
// ---------------------------------------------------------------------------
__global__ __launch_bounds__(256) void gemm_fused(
    const short* __restrict__ y, const short* __restrict__ WcT,
    const short* __restrict__ xb, const float* __restrict__ bc,
    const short* __restrict__ WaT,
    const float* __restrict__ lng, const float* __restrict__ lnb,
    const float* __restrict__ a_src, const float* __restrict__ a_tgt,
    short* __restrict__ hb, float* __restrict__ es, float* __restrict__ et)
{
    __shared__ __align__(16) short lB[256 * LDP];   // 36864B
    __shared__ __align__(16) short lZ[32 * ZLDP];   // 16896B (y, then LN(z))
    __shared__ float red_s[64], red_q[64];          // [2][32]
    int t = threadIdx.x;
    int m0 = blockIdx.x * SROWS;
    int lane = t & 63, wid = t >> 6;
    int wm = wid & 1, wn = wid >> 1;
    int lm = lane & 15, lk = (lane >> 4) * 8;
    int rbase = (lane >> 4) * 4;

    // stage full y tile (32 x 256) into lZ once (coalesced)
#pragma unroll
    for (int c = 0; c < 4; ++c) {
        int idx = c * 256 + t;
        int r = idx >> 5, kg = idx & 31;
        *(bf16x8*)(lZ + r * ZLDP + kg * 8) =
            *(const bf16x8*)(y + (size_t)(m0 + r) * HD + kg * 8);
    }

    // ---- Phase 1: z = y@Wc ----
    f32x4 acc[8] = {};
    for (int kt = 0; kt < 4; ++kt) {
        __syncthreads();               // covers y-stage (kt=0) and lB reads (kt>0)
        stage_w(WcT, HD, kt * 64, lB);
        __syncthreads();
#pragma unroll
        for (int kk2 = 0; kk2 < 64; kk2 += 32) {
            bf16x8 a = *(const bf16x8*)(lZ + (wm * 16 + lm) * ZLDP + kt * 64 + kk2 + lk);
#pragma unroll
            for (int j = 0; j < 8; ++j) {
                bf16x8 b = *(const bf16x8*)(lB + (wn * 128 + j * 16 + lm) * LDP + kk2 + lk);
                acc[j] = __builtin_amdgcn_mfma_f32_16x16x32_bf16(a, b, acc[j], 0, 0, 0);
            }
        }
    }
    float zv[8][4];
    float s4r[4] = {}, q4r[4] = {};
#pragma unroll
    for (int j = 0; j < 8; ++j)
#pragma unroll
        for (int r = 0; r < 4; ++r) {
            int n = wn * 128 + j * 16 + lm;
            int row = m0 + wm * 16 + rbase + r;
            float z = acc[j][r] + bc[n] + bf2f(xb[(size_t)row * HD + n]);
            zv[j][r] = z; s4r[r] += z; q4r[r] += z * z;
        }
#pragma unroll
    for (int r = 0; r < 4; ++r)
#pragma unroll
        for (int o = 1; o < 16; o <<= 1) {
            s4r[r] += __shfl_xor(s4r[r], o, 64);
            q4r[r] += __shfl_xor(q4r[r], o, 64);
        }
    if (lm == 0)
#pragma unroll
        for (int r = 0; r < 4; ++r) {
            red_s[wn * 32 + wm * 16 + rbase + r] = s4r[r];
            red_q[wn * 32 + wm * 16 + rbase + r] = q4r[r];
        }
    __syncthreads();   // stats ready AND all phase-1 lZ reads done before overwrite
    float mu[4], inv[4];
#pragma unroll
    for (int r = 0; r < 4; ++r) {
        int rowl = wm * 16 + rbase + r;
        float S = red_s[rowl] + red_s[32 + rowl];
        float Q = red_q[rowl] + red_q[32 + rowl];
        mu[r] = S * (1.f / HD);
        inv[r] = rsqrtf(Q * (1.f / HD) - mu[r] * mu[r] + EPSV);
    }
#pragma unroll
    for (int j = 0; j < 8; ++j)
#pragma unroll
        for (int r = 0; r < 4; ++r) {
            int n = wn * 128 + j * 16 + lm;
            int rowl = wm * 16 + rbase + r;
            lZ[rowl * ZLDP + n] = f2bf((zv[j][r] - mu[r]) * inv[r] * lng[n] + lnb[n]);
        }

    // ---- Phase 2: h = LN(z) @ Wa ----
    f32x4 acc2[8] = {};
    for (int kt = 0; kt < 4; ++kt) {
        __syncthreads();               // LN(z) writes visible; prior lB reads done
        stage_w(WaT, HD, kt * 64, lB);
        __syncthreads();
#pragma unroll
        for (int kk2 = 0; kk2 < 64; kk2 += 32) {
            bf16x8 a = *(const bf16x8*)(lZ + (wm * 16 + lm) * ZLDP + kt * 64 + kk2 + lk);
#pragma unroll
            for (int j = 0; j < 8; ++j) {
                bf16x8 b = *(const bf16x8*)(lB + (wn * 128 + j * 16 + lm) * LDP + kk2 + lk);
                acc2[j] = __builtin_amdgcn_mfma_f32_16x16x32_bf16(a, b, acc2[j], 0, 0, 0);
            }
        }
    }
    float esA[4] = {}, etA[4] = {}, esB[4] = {}, etB[4] = {};
#pragma unroll
    for (int j = 0; j < 8; ++j) {
        int n = wn * 128 + j * 16 + lm;
        float as = a_src[n], at = a_tgt[n];
#pragma unroll
        for (int r = 0; r < 4; ++r) {
            int row = m0 + wm * 16 + rbase + r;
            hb[(size_t)row * HD + n] = f2bf(acc2[j][r]);
            if (j < 4) { esA[r] += acc2[j][r] * as; etA[r] += acc2[j][r] * at; }
            else       { esB[r] += acc2[j][r] * as; etB[r] += acc2[j][r] * at; }
        }
    }
#pragma unroll
    for (int r = 0; r < 4; ++r) {
#pragma unroll
        for (int o = 1; o < 16; o <<= 1) {
            esA[r] += __shfl_xor(esA[r], o, 64);
            etA[r] += __shfl_xor(etA[r], o, 64);
            esB[r] += __shfl_xor(esB[r], o, 64);
            etB[r] += __shfl_xor(etB[r], o, 64);
        }
        if (lm == 0) {
            int row = m0 + wm * 16 + rbase + r;
            es[row * NHEADS + wn * 2 + 0] = esA[r];
            et[row * NHEADS + wn * 2 + 0] = etA[r];
            es[row * NHEADS + wn * 2 + 1] = esB[r];
            et[row * NHEADS + wn * 2 + 1] = etB[r];
        }
    }
}

// ---------------------------------------------------------------------------
// Fused tail (round-11 proven version): block owns 32 rows.
//  Phase A: attn + LN -> gs2 in LDS (h halo + xb staged in LDS)
//  Pass 1: accg = xb@Wg_top (A from lX); Pass 2: += gs2@Wg_bot; Pass 3: gs2@Wp
//  epilogue: out = lX + sigmoid(accg+bg)*(accp+bp)
// LDS: union(lH 24.8K, lB 36.9K) + lZ 16.9K + lX 16.9K = 70.7K -> 2 blocks/CU
// ---------------------------------------------------------------------------
#define AF_LZ_OFF (256 * LDP * 2)
#define AF_LX_OFF (256 * LDP * 2 + 32 * ZLDP * 2)

__global__ __launch_bounds__(256) void attn_final(
    const short* __restrict__ hb, const float* __restrict__ es,
    const float* __restrict__ et, const short* __restrict__ xb,
    const float* __restrict__ ba, const float* __restrict__ lng,
    const float* __restrict__ lnb,
    const short* __restrict__ WgT, const float* __restrict__ bg,
    const short* __restrict__ WpT, const float* __restrict__ bp,
    float* __restrict__ out)
{
    __shared__ __align__(16) char smem[256 * LDP * 2 + 2 * 32 * ZLDP * 2];
    short* lH = (short*)smem;                 // 47 x SLDP during attn
    short* lB = (short*)smem;                 // 256 x LDP during GEMMs
    short* lZ = (short*)(smem + AF_LZ_OFF);   // gs2, 32 x ZLDP
    short* lX = (short*)(smem + AF_LX_OFF);   // xb,  32 x ZLDP

    int t = threadIdx.x;
    int t0 = blockIdx.x * SROWS;
    int batch_base = t0 & ~(SEQ - 1);

    // stage h halo tile + xb own rows
    for (int i = t; i < (SROWS + SHALO) * 64; i += 256) {
        int r = i >> 6, c4 = (i & 63) * 4;
        int grow = t0 - 7 + r;
        short4 v = {0, 0, 0, 0};
        if (grow >= batch_base && grow < batch_base + SEQ)
            v = *(const short4*)(hb + (size_t)grow * HD + c4);
        *(short4*)(lH + r * SLDP + c4) = v;
    }
    for (int i = t; i < SROWS * 64; i += 256) {
        int r = i >> 6, c4 = (i & 63) * 4;
        *(short4*)(lX + r * ZLDP + c4) = *(const short4*)(xb + (size_t)(t0 + r) * HD + c4);
    }
    __syncthreads();

    // ---- Phase A: attn + LN -> lZ ----
    int wv = t >> 6, lane = t & 63;
    int tap = lane >> 2, hh = lane & 3;
    int hd = lane >> 4;
    int c0 = lane * 4;
    for (int rr = wv; rr < SROWS; rr += 4) {
        int trow = t0 + rr;
        int p = trow & (SEQ - 1);
        float lg = -1e30f, wd = 0.f;
        bool okk = false;
        if (tap < 15) {
            int d = (tap < 7) ? (tap - 7) : (tap - 6);
            int qp = p + d;
            okk = (qp >= 0) && (qp < SEQ);
            if (okk) {
                float l = es[(trow + d) * NHEADS + hh] + et[trow * NHEADS + hh];
                lg = (l > 0.f) ? l : 0.2f * l;
            }
            wd = 1.f / (1.f + (float)((d < 0) ? -d : d));
        }
        float m = lg;
#pragma unroll
        for (int o = 4; o < 64; o <<= 1) m = fmaxf(m, __shfl_xor(m, o, 64));
        float un = okk ? __expf(lg - m) * wd : 0.f;
        float den = un;
#pragma unroll
        for (int o = 4; o < 64; o <<= 1) den += __shfl_xor(den, o, 64);
        float alpha_l = un / (den + 1e-9f);

        float al[15];
#pragma unroll
        for (int i = 0; i < 15; ++i) al[i] = __shfl(alpha_l, i * 4 + hd, 64);

        float a0 = 0.f, a1 = 0.f, a2 = 0.f, a3 = 0.f;
#pragma unroll
        for (int i = 0; i < 15; ++i) {
            int d = (i < 7) ? (i - 7) : (i - 6);
            short4 s4 = *(const short4*)(lH + (rr + 7 + d) * SLDP + c0);
            a0 += al[i] * bf2f(s4.x); a1 += al[i] * bf2f(s4.y);
            a2 += al[i] * bf2f(s4.z); a3 += al[i] * bf2f(s4.w);
        }
        short4 xv4 = *(const short4*)(lX + rr * ZLDP + c0);
        float4 bav = *(const float4*)(ba + c0);
        float v0 = a0 + bav.x + bf2f(xv4.x), v1 = a1 + bav.y + bf2f(xv4.y);
        float v2 = a2 + bav.z + bf2f(xv4.z), v3 = a3 + bav.w + bf2f(xv4.w);
        float s = v0 + v1 + v2 + v3;
        float q = v0 * v0 + v1 * v1 + v2 * v2 + v3 * v3;
#pragma unroll
        for (int o = 1; o < 64; o <<= 1) { s += __shfl_xor(s, o, 64); q += __shfl_xor(q, o, 64); }
        float mu = s * (1.f / HD);
        float var = q * (1.f / HD) - mu * mu;
        float inv = rsqrtf(var + EPSV);
        float4 gv = *(const float4*)(lng + c0);
        float4 bv = *(const float4*)(lnb + c0);
        short4 o4;
        o4.x = f2bf((v0 - mu) * inv * gv.x + bv.x);
        o4.y = f2bf((v1 - mu) * inv * gv.y + bv.y);
        o4.z = f2bf((v2 - mu) * inv * gv.z + bv.z);
        o4.w = f2bf((v3 - mu) * inv * gv.w + bv.w);
        *(short4*)(lZ + rr * ZLDP + c0) = o4;
    }

    // ---- Phases B/C: three staged GEMM passes ----
    int wid = t >> 6;
    int wm = wid & 1, wn = wid >> 1;
    int lm = lane & 15, lk = (lane >> 4) * 8;
    int rbase = (lane >> 4) * 4;
    f32x4 accg[8] = {}, accp[8] = {};
    // pass 1: accg = xb @ Wg_top (A from lX)
    for (int kt = 0; kt < 4; ++kt) {
        __syncthreads();
        stage_w(WgT, 512, kt * 64, lB);
        __syncthreads();
#pragma unroll
        for (int kk2 = 0; kk2 < 64; kk2 += 32) {
            bf16x8 a = *(const bf16x8*)(lX + (wm * 16 + lm) * ZLDP + kt * 64 + kk2 + lk);
#pragma unroll
            for (int j = 0; j < 8; ++j) {
                bf16x8 b = *(const bf16x8*)(lB + (wn * 128 + j * 16 + lm) * LDP + kk2 + lk);
                accg[j] = __builtin_amdgcn_mfma_f32_16x16x32_bf16(a, b, accg[j], 0, 0, 0);
            }
        }
    }
    // pass 2: accg += gs2 @ Wg_bot
    for (int kt = 0; kt < 4; ++kt) {
        __syncthreads();
        stage_w(WgT, 512, 256 + kt * 64, lB);
        __syncthreads();
#pragma unroll
        for (int kk2 = 0; kk2 < 64; kk2 += 32) {
            bf16x8 a = *(const bf16x8*)(lZ + (wm * 16 + lm) * ZLDP + kt * 64 + kk2 + lk);
#pragma unroll
            for (int j = 0; j < 8; ++j) {
                bf16x8 b = *(const bf16x8*)(lB + (wn * 128 + j * 16 + lm) * LDP + kk2 + lk);
                accg[j] = __builtin_amdgcn_mfma_f32_16x16x32_bf16(a, b, accg[j], 0, 0, 0);
            }
        }
    }
    // pass 3: accp = gs2 @ Wp
    for (int kt = 0; kt < 4; ++kt) {
        __syncthreads();
        stage_w(WpT, HD, kt * 64, lB);
        __syncthreads();
#pragma unroll
        for (int kk2 = 0; kk2 < 64; kk2 += 32) {
            bf16x8 a = *(const bf16x8*)(lZ + (wm * 16 + lm) * ZLDP + kt * 64 + kk2 + lk);
#pragma unroll
            for (int j = 0; j < 8; ++j) {
                bf16x8 b = *(const bf16x8*)(lB + (wn * 128 + j * 16 + lm) * LDP + kk2 + lk);
                accp[j] = __builtin_amdgcn_mfma_f32_16x16x32_bf16(a, b, accp[j], 0, 0, 0);
            }
        }
    }
    // epilogue
#pragma unroll
    for (int j = 0; j < 8; ++j)
#pragma unroll
        for (int r = 0; r < 4; ++r) {
            int n = wn * 128 + j * 16 + lm;
            int rowl = wm * 16 + rbase + r;
            size_t m = (size_t)(t0 + rowl);
            float gate = 1.f / (1.f + __expf(-(accg[j][r] + bg[n])));
            float pv = accp[j][r] + bp[n];
            out[m * HD + n] = bf2f(lX[rowl * ZLDP + n]) + gate * pv;
        }
}

// ---------------------------------------------------------------------------
extern "C" void kernel_launch(void* const* d_in, const int* in_sizes, int n_in,
                              void* d_out, int out_size, void* d_ws, size_t ws_size,
                              hipStream_t stream)
{
    const float* x     = (const float*)d_in[0];
    const float* Wc    = (const float*)d_in[1];
    const float* bc    = (const float*)d_in[2];
    const float* Wa    = (const float*)d_in[3];
    const float* a_src = (const float*)d_in[4];
    const float* a_tgt = (const float*)d_in[5];
    const float* ba    = (const float*)d_in[6];
    const float* ln_g  = (const float*)d_in[7];
    const float* ln_b  = (const float*)d_in[8];
    const float* Wg    = (const float*)d_in[9];
    const float* bg    = (const float*)d_in[10];
    const float* Wp    = (const float*)d_in[11];
    const float* bp    = (const float*)d_in[12];

    float* out = (float*)d_out;      // written only by attn_final

    char* w = (char*)d_ws;
    short* y   = (short*)w;   w += (size_t)NR * HD * 2;   // stencil(x) bf16
    short* xb  = (short*)w;   w += (size_t)NR * HD * 2;   // bf16 x
    short* hb  = (short*)w;   w += (size_t)NR * HD * 2;   // h bf16
    float* es  = (float*)w;   w += (size_t)NR * NHEADS * 4;
    float* et  = (float*)w;   w += (size_t)NR * NHEADS * 4;
    short* WcT = (short*)w;   w += 256 * 256 * 2;
    short* WaT = (short*)w;   w += 256 * 256 * 2;
    short* WpT = (short*)w;   w += 256 * 256 * 2;
    short* WgT = (short*)w;   w += 512 * 256 * 2;

    // 0) merged: stencil+cast / weights^T
    prep_stencil<<<dim3(NR / SROWS, 5), 256, 0, stream>>>(
        x, Wc, Wa, Wg, Wp, xb, y, WcT, WaT, WgT, WpT);
    // 1) fused: z=y@Wc+bc+xb -> LN -> h=LN(z)@Wa -> es/et   (z stays in LDS)
    gemm_fused<<<NR / SROWS, 256, 0, stream>>>(y, WcT, xb, bc, WaT, ln_g, ln_b,
                                               a_src, a_tgt, hb, es, et);
    // 2) fused: gs2 = LN(attn(h)+ba+xb) in LDS -> out = xb + gate*(gs2@Wp+bp)
    attn_final<<<NR / SROWS, 256, 0, stream>>>(hb, es, et, xb, ba, ln_g, ln_b,
                                               WgT, bg, WpT, bp, out);
}